// Round 1
// baseline (8148.119 us; speedup 1.0000x reference)
//
#include <hip/hip_runtime.h>
#include <hip/hip_bf16.h>

#define L_ 2
#define T_ 512
#define B_ 128
#define F_ 4
#define H_ 256

// Static device buffers (rewritten every call; no hipMalloc needed)
__device__ __hip_bfloat16 g_Uh[L_][4][H_][H_];   // expanded recurrent weights, bf16 (1 MB)
__device__ float          g_Wx[L_][4][F_][H_];   // expanded input weights (32 KB)
__device__ float          g_inter[T_][B_][F_];   // layer-1 normalized output (1 MB)

// Quaternion sign table: W block (a=input comp row, q=output comp col)
// negative iff bit (a*4+q) of 0x5390 is set; component index = a^q.
__device__ __forceinline__ float qsign(int a, int q) {
  return ((0x5390 >> (a * 4 + q)) & 1) ? -1.f : 1.f;
}

__global__ void expand_uh(const float* __restrict__ r_, const float* __restrict__ i_,
                          const float* __restrict__ j_, const float* __restrict__ k_) {
  int idx = blockIdx.x * 256 + threadIdx.x;        // 2*4*256*256 total
  int col = idx & 255;
  int row = (idx >> 8) & 255;
  int g   = (idx >> 16) & 3;
  int l   = idx >> 18;
  int a = row >> 6, p = row & 63;
  int q = col >> 6, c = col & 63;
  const float* comp[4] = {r_, i_, j_, k_};
  float v = qsign(a, q) * comp[a ^ q][((l * 4 + g) * 64 + p) * 64 + c];
  g_Uh[l][g][row][col] = __float2bfloat16(v);
}

__global__ void expand_wx(const float* __restrict__ r_, const float* __restrict__ i_,
                          const float* __restrict__ j_, const float* __restrict__ k_) {
  int idx = blockIdx.x * 256 + threadIdx.x;        // 2*4*4*256 total
  int col = idx & 255;
  int a   = (idx >> 8) & 3;
  int g   = (idx >> 10) & 3;
  int l   = idx >> 12;
  int q = col >> 6, c = col & 63;
  const float* comp[4] = {r_, i_, j_, k_};
  float v = qsign(a, q) * comp[a ^ q][((l * 4 + g) * 1 + 0) * 64 + c];
  g_Wx[l][g][a][col] = v;
}

// One workgroup per batch element; 256 threads.
// Matvec phase: thread t computes gate (t>>6), columns 4*(t&63)..+3.
// Update phase: thread t owns h/c index t.
__launch_bounds__(256)
__global__ void qlstm_layer(const float* __restrict__ x_in,  // [B][T][F] (layer 0 only)
                            const float* __restrict__ wb,    // [4][H]
                            const float* __restrict__ fw,    // [H][F]
                            const float* __restrict__ fb,    // [F]
                            int layer,
                            float* __restrict__ out_final)   // d_out for last layer else null
{
  __shared__ float sh_h[H_];
  __shared__ float sh_pre[4][H_];
  __shared__ float sh_x[2][F_];
  __shared__ float sh_wx[4][F_][H_];
  __shared__ float sh_wb[4][H_];
  __shared__ float sh_fw[H_][F_];
  __shared__ float sh_fb[F_];
  __shared__ float sh_red[4][F_];

  const int t = threadIdx.x;
  const int b = blockIdx.x;

  // ---- stage per-layer weights into LDS ----
  for (int g = 0; g < 4; ++g) {
    for (int f = 0; f < F_; ++f) sh_wx[g][f][t] = g_Wx[layer][g][f][t];
    sh_wb[g][t] = wb[g * H_ + t];
  }
  {
    float4 fv = *(const float4*)(fw + t * 4);
    sh_fw[t][0] = fv.x; sh_fw[t][1] = fv.y; sh_fw[t][2] = fv.z; sh_fw[t][3] = fv.w;
  }
  if (t < F_) sh_fb[t] = fb[t];
  if (t == 0) {
    const float* xp = (layer == 0) ? (x_in + (b * T_ + 0) * F_) : &g_inter[0][b][0];
    float4 xv = *(const float4*)xp;
    sh_x[0][0] = xv.x; sh_x[0][1] = xv.y; sh_x[0][2] = xv.z; sh_x[0][3] = xv.w;
  }
  sh_h[t] = 0.f;
  float c_state = 0.f;
  __syncthreads();

  const int gt = t >> 6;
  const int c0 = (t & 63) * 4;
  const __hip_bfloat16* up_base = &g_Uh[layer][gt][0][c0];
  const int wv = t >> 6;
  const int lane = t & 63;

  for (int step = 0; step < T_; ++step) {
    // ---- phase A: prefetch next x; matvec pre = g + Uh*h ----
    if (t == 255 && step + 1 < T_) {
      const float* xp = (layer == 0) ? (x_in + (b * T_ + (step + 1)) * F_)
                                     : &g_inter[step + 1][b][0];
      float4 xv = *(const float4*)xp;
      float* dst = &sh_x[(step + 1) & 1][0];
      dst[0] = xv.x; dst[1] = xv.y; dst[2] = xv.z; dst[3] = xv.w;
    }
    const float x0 = sh_x[step & 1][0], x1 = sh_x[step & 1][1];
    const float x2 = sh_x[step & 1][2], x3 = sh_x[step & 1][3];

    float acc0 = sh_wb[gt][c0 + 0] + x0 * sh_wx[gt][0][c0 + 0] + x1 * sh_wx[gt][1][c0 + 0]
                                   + x2 * sh_wx[gt][2][c0 + 0] + x3 * sh_wx[gt][3][c0 + 0];
    float acc1 = sh_wb[gt][c0 + 1] + x0 * sh_wx[gt][0][c0 + 1] + x1 * sh_wx[gt][1][c0 + 1]
                                   + x2 * sh_wx[gt][2][c0 + 1] + x3 * sh_wx[gt][3][c0 + 1];
    float acc2 = sh_wb[gt][c0 + 2] + x0 * sh_wx[gt][0][c0 + 2] + x1 * sh_wx[gt][1][c0 + 2]
                                   + x2 * sh_wx[gt][2][c0 + 2] + x3 * sh_wx[gt][3][c0 + 2];
    float acc3 = sh_wb[gt][c0 + 3] + x0 * sh_wx[gt][0][c0 + 3] + x1 * sh_wx[gt][1][c0 + 3]
                                   + x2 * sh_wx[gt][2][c0 + 3] + x3 * sh_wx[gt][3][c0 + 3];

    const __hip_bfloat16* up = up_base;
    #pragma unroll 8
    for (int r = 0; r < H_; ++r) {
      float hr = sh_h[r];
      uint2 w = *(const uint2*)up;      // 4 bf16 weights, coalesced 8B/lane
      up += H_;
      acc0 += hr * __uint_as_float(w.x << 16);
      acc1 += hr * __uint_as_float(w.x & 0xffff0000u);
      acc2 += hr * __uint_as_float(w.y << 16);
      acc3 += hr * __uint_as_float(w.y & 0xffff0000u);
    }
    sh_pre[gt][c0 + 0] = acc0;
    sh_pre[gt][c0 + 1] = acc1;
    sh_pre[gt][c0 + 2] = acc2;
    sh_pre[gt][c0 + 3] = acc3;
    __syncthreads();   // barrier 1

    // ---- phase B: gate nonlinearities + state update (thread t = h-index t) ----
    float pf = sh_pre[0][t], pi = sh_pre[1][t], po = sh_pre[2][t], pc = sh_pre[3][t];
    float fg = 1.f / (1.f + expf(-pf));
    float ig = 1.f / (1.f + expf(-pi));
    float og = 1.f / (1.f + expf(-po));
    float cc = tanhf(pc);
    c_state = ig * cc + fg * c_state;
    float h = og * tanhf(c_state);
    sh_h[t] = h;

    const bool do_proj = (out_final == nullptr) || (step == T_ - 1);
    if (do_proj) {
      float p0 = h * sh_fw[t][0];
      float p1 = h * sh_fw[t][1];
      float p2 = h * sh_fw[t][2];
      float p3 = h * sh_fw[t][3];
      #pragma unroll
      for (int off = 32; off > 0; off >>= 1) {
        p0 += __shfl_down(p0, off, 64);
        p1 += __shfl_down(p1, off, 64);
        p2 += __shfl_down(p2, off, 64);
        p3 += __shfl_down(p3, off, 64);
      }
      if (lane == 0) {
        sh_red[wv][0] = p0; sh_red[wv][1] = p1; sh_red[wv][2] = p2; sh_red[wv][3] = p3;
      }
    }
    __syncthreads();   // barrier 2

    if (do_proj && t < F_) {
      float o0 = sh_red[0][0] + sh_red[1][0] + sh_red[2][0] + sh_red[3][0] + sh_fb[0];
      float o1 = sh_red[0][1] + sh_red[1][1] + sh_red[2][1] + sh_red[3][1] + sh_fb[1];
      float o2 = sh_red[0][2] + sh_red[1][2] + sh_red[2][2] + sh_red[3][2] + sh_fb[2];
      float o3 = sh_red[0][3] + sh_red[1][3] + sh_red[2][3] + sh_red[3][3] + sh_fb[3];
      float nrm = sqrtf(o0 * o0 + o1 * o1 + o2 * o2 + o3 * o3);
      nrm = fmaxf(nrm, 1e-12f);
      float vals[4] = {o0 / nrm, o1 / nrm, o2 / nrm, o3 / nrm};
      if (out_final) out_final[b * F_ + t] = vals[t];
      else           g_inter[step][b][t] = vals[t];
    }
  }
}

extern "C" void kernel_launch(void* const* d_in, const int* in_sizes, int n_in,
                              void* d_out, int out_size, void* d_ws, size_t ws_size,
                              hipStream_t stream) {
  const float* x   = (const float*)d_in[0];
  const float* wxr = (const float*)d_in[1];
  const float* wxi = (const float*)d_in[2];
  const float* wxj = (const float*)d_in[3];
  const float* wxk = (const float*)d_in[4];
  const float* wxb = (const float*)d_in[5];
  const float* uhr = (const float*)d_in[6];
  const float* uhi = (const float*)d_in[7];
  const float* uhj = (const float*)d_in[8];
  const float* uhk = (const float*)d_in[9];
  const float* fcw = (const float*)d_in[10];
  const float* fcb = (const float*)d_in[11];
  float* out = (float*)d_out;

  expand_uh<<<dim3((L_ * 4 * H_ * H_) / 256), dim3(256), 0, stream>>>(uhr, uhi, uhj, uhk);
  expand_wx<<<dim3((L_ * 4 * F_ * H_) / 256), dim3(256), 0, stream>>>(wxr, wxi, wxj, wxk);

  for (int l = 0; l < L_; ++l) {
    qlstm_layer<<<dim3(B_), dim3(256), 0, stream>>>(
        x, wxb + l * 4 * H_, fcw + l * H_ * F_, fcb + l * F_, l,
        (l == L_ - 1) ? out : nullptr);
  }
}

// Round 2
// 3805.490 us; speedup vs baseline: 2.1411x; 2.1411x over previous
//
#include <hip/hip_runtime.h>
#include <hip/hip_bf16.h>

#define L_ 2
#define T_ 512
#define B_ 128
#define F_ 4
#define H_ 256

// layer-1 normalized output sequence (fully rewritten every call)
__device__ float g_inter[T_][B_][F_];

// f32 -> bf16 round-to-nearest-even (bit trick, matches __float2bfloat16)
__device__ __forceinline__ unsigned f2bf(float f) {
  unsigned u = __float_as_uint(f);
  unsigned r = u + 0x7fff + ((u >> 16) & 1);
  return r >> 16;
}
__device__ __forceinline__ float bfl(unsigned v) { return __uint_as_float(v << 16); }
__device__ __forceinline__ float bfh(unsigned v) { return __uint_as_float(v & 0xffff0000u); }

__device__ __forceinline__ float fast_sigmoid(float x) {
  return 1.f / (1.f + __expf(-x));
}
__device__ __forceinline__ float fast_tanh(float x) {
  float a = fabsf(x);
  float e = __expf(2.f * a);
  float r = 1.f - 2.f / (e + 1.f);
  return copysignf(r, x);
}

// Quaternion sign: W[a*64+p][q*64+c] = sign(a,q) * comp[a^q][p][c];
// negative iff bit (a*4+q) of 0x5390 set.
#define QSIGN_MASK 0x5390

// One WG per batch element, 256 threads (4 waves).
// Matvec mapping: thread t -> gate gt=t>>6, column u=t&63; computes pre[gt][q*64+u], q=0..3.
// Update mapping: thread t -> hidden index t.
// Recurrent weights live in dynamic LDS as bf16, layout [g][d][p8][u][p_lo(8)], 16B units.
__launch_bounds__(256, 1)
__global__ void qlstm_layer(const float* __restrict__ x_in,
                            const float* __restrict__ uhr, const float* __restrict__ uhi,
                            const float* __restrict__ uhj, const float* __restrict__ uhk,
                            const float* __restrict__ wxr, const float* __restrict__ wxi,
                            const float* __restrict__ wxj, const float* __restrict__ wxk,
                            const float* __restrict__ wb,
                            const float* __restrict__ fw, const float* __restrict__ fb,
                            int layer, float* __restrict__ out_final)
{
  extern __shared__ uint4 smw4[];                      // 131072 B recurrent weights (bf16)
  char* smw = (char*)smw4;
  __shared__ ushort4 sh_wxh[4][256];                   // 8 KB  expanded Wx (bf16x4 per col)
  __shared__ float   sh_wb[4][256];                    // 4 KB  gate bias
  __shared__ float   sh_pre[4][256];                   // 4 KB  gate pre-activations
  __shared__ __align__(16) unsigned short sh_hb[256];  // 512 B h state (bf16)
  __shared__ float4  sh_fw[256];                       // 4 KB  fco weights per hidden idx
  __shared__ float4  sh_prod[256];                     // 4 KB  per-hidden projection partials
  __shared__ float   sh_x[2][4];
  __shared__ float   sh_fb[4];

  const int t  = threadIdx.x;
  const int b  = blockIdx.x;
  const int gt = t >> 6;
  const int u  = t & 63;

  // ---------------- stage recurrent weight components into LDS (bf16) ----------------
  {
    const float* C[4] = {uhr, uhi, uhj, uhk};
    for (int pe = t; pe < 32768; pe += 256) {      // 32768 bf16-pairs = 65536 weights
      int uu = pe & 63;
      int ph = (pe >> 6) & 31;                     // p0 = 2*ph
      int d  = (pe >> 11) & 3;
      int g  = (pe >> 13) & 3;
      int p0 = ph * 2;
      const float* src = C[d] + ((layer * 4 + g) * 64 + p0) * 64 + uu;
      unsigned lo = f2bf(src[0]);
      unsigned hi = f2bf(src[64]);
      unsigned off = (unsigned)((((g * 4 + d) * 8 + (p0 >> 3)) * 64 + uu) * 16 + (p0 & 7) * 2);
      *(unsigned*)(smw + off) = lo | (hi << 16);
    }
  }
  // ---------------- stage expanded input weights + bias ----------------
  {
    const float* X[4] = {wxr, wxi, wxj, wxk};
    #pragma unroll
    for (int m = 0; m < 4; ++m) {
      int idx = m * 256 + t;                       // (g, col)
      int g = idx >> 8, col = idx & 255;
      int q = col >> 6, c = col & 63;
      unsigned pk[4];
      #pragma unroll
      for (int a = 0; a < 4; ++a) {
        float v = X[a ^ q][(layer * 4 + g) * 64 + c];
        if ((QSIGN_MASK >> (a * 4 + q)) & 1) v = -v;
        pk[a] = f2bf(v);
      }
      sh_wxh[g][col] = make_ushort4((unsigned short)pk[0], (unsigned short)pk[1],
                                    (unsigned short)pk[2], (unsigned short)pk[3]);
      sh_wb[g][col] = wb[g * 256 + col];
    }
  }
  sh_fw[t] = *(const float4*)(fw + t * 4);
  if (t < 4) sh_fb[t] = fb[t];
  if (t == 0) {
    const float* xp = (layer == 0) ? (x_in + b * T_ * F_) : &g_inter[0][b][0];
    *(float4*)&sh_x[0][0] = *(const float4*)xp;
  }
  sh_hb[t] = 0;
  float c_state = 0.f;
  __syncthreads();

  // hoist per-thread constants out of the step loop
  float wxf[4][4], wbv[4];
  #pragma unroll
  for (int q = 0; q < 4; ++q) {
    ushort4 wv = sh_wxh[gt][q * 64 + u];
    wxf[q][0] = bfl(wv.x); wxf[q][1] = bfl(wv.y);
    wxf[q][2] = bfl(wv.z); wxf[q][3] = bfl(wv.w);
    wbv[q] = sh_wb[gt][q * 64 + u];
  }
  const float4 fw4 = sh_fw[t];
  char* wtb = smw + gt * 32768 + u * 16;
  const char* hbb = (const char*)sh_hb;

  for (int step = 0; step < T_; ++step) {
    // ---- phase A: prefetch x, reduce prev projection (layer0), matvec ----
    if (t == 255 && step + 1 < T_) {
      const float* xp = (layer == 0) ? (x_in + (b * T_ + step + 1) * F_)
                                     : &g_inter[step + 1][b][0];
      *(float4*)&sh_x[(step + 1) & 1][0] = *(const float4*)xp;
    }
    if (out_final == nullptr && step > 0 && t < 64) {
      float4 s0 = sh_prod[t], s1 = sh_prod[64 + t], s2 = sh_prod[128 + t], s3 = sh_prod[192 + t];
      float p0 = s0.x + s1.x + s2.x + s3.x;
      float p1 = s0.y + s1.y + s2.y + s3.y;
      float p2 = s0.z + s1.z + s2.z + s3.z;
      float p3 = s0.w + s1.w + s2.w + s3.w;
      #pragma unroll
      for (int off = 32; off; off >>= 1) {
        p0 += __shfl_down(p0, off, 64);
        p1 += __shfl_down(p1, off, 64);
        p2 += __shfl_down(p2, off, 64);
        p3 += __shfl_down(p3, off, 64);
      }
      if (t == 0) {
        p0 += sh_fb[0]; p1 += sh_fb[1]; p2 += sh_fb[2]; p3 += sh_fb[3];
        float nrm = fmaxf(sqrtf(p0 * p0 + p1 * p1 + p2 * p2 + p3 * p3), 1e-12f);
        float inv = 1.f / nrm;
        *(float4*)&g_inter[step - 1][b][0] = make_float4(p0 * inv, p1 * inv, p2 * inv, p3 * inv);
      }
    }

    const float x0 = sh_x[step & 1][0], x1 = sh_x[step & 1][1];
    const float x2 = sh_x[step & 1][2], x3 = sh_x[step & 1][3];
    float acc[4];
    float2 a2[4];
    #pragma unroll
    for (int q = 0; q < 4; ++q) {
      acc[q] = wbv[q] + x0 * wxf[q][0] + x1 * wxf[q][1] + x2 * wxf[q][2] + x3 * wxf[q][3];
      a2[q] = make_float2(0.f, 0.f);
    }

    #pragma unroll
    for (int p8 = 0; p8 < 8; ++p8) {
      uint4 hv[4];
      #pragma unroll
      for (int a = 0; a < 4; ++a)
        hv[a] = *(const uint4*)(hbb + a * 128 + p8 * 16);
      float2 hf[4][4];
      #pragma unroll
      for (int a = 0; a < 4; ++a) {
        hf[a][0] = make_float2(bfl(hv[a].x), bfh(hv[a].x));
        hf[a][1] = make_float2(bfl(hv[a].y), bfh(hv[a].y));
        hf[a][2] = make_float2(bfl(hv[a].z), bfh(hv[a].z));
        hf[a][3] = make_float2(bfl(hv[a].w), bfh(hv[a].w));
      }
      #pragma unroll
      for (int d = 0; d < 4; ++d) {
        uint4 wv = *(const uint4*)(wtb + d * 8192 + p8 * 1024);
        float2 wf[4];
        wf[0] = make_float2(bfl(wv.x), bfh(wv.x));
        wf[1] = make_float2(bfl(wv.y), bfh(wv.y));
        wf[2] = make_float2(bfl(wv.z), bfh(wv.z));
        wf[3] = make_float2(bfl(wv.w), bfh(wv.w));
        #pragma unroll
        for (int q = 0; q < 4; ++q) {
          const int a = d ^ q;
          const bool neg = (QSIGN_MASK >> (a * 4 + q)) & 1;
          #pragma unroll
          for (int j = 0; j < 4; ++j) {
            if (neg) a2[q] -= wf[j] * hf[a][j];
            else     a2[q] += wf[j] * hf[a][j];
          }
        }
      }
    }
    #pragma unroll
    for (int q = 0; q < 4; ++q)
      sh_pre[gt][q * 64 + u] = acc[q] + a2[q].x + a2[q].y;
    __syncthreads();   // barrier 1

    // ---- phase B: gates + state update (thread t = hidden index t) ----
    float pf = sh_pre[0][t], pi = sh_pre[1][t], po = sh_pre[2][t], pc = sh_pre[3][t];
    float fg = fast_sigmoid(pf);
    float ig = fast_sigmoid(pi);
    float og = fast_sigmoid(po);
    float cc = fast_tanh(pc);
    c_state = ig * cc + fg * c_state;
    float h = og * fast_tanh(c_state);
    sh_hb[t] = (unsigned short)f2bf(h);
    if (out_final == nullptr || step == T_ - 1)
      sh_prod[t] = make_float4(h * fw4.x, h * fw4.y, h * fw4.z, h * fw4.w);
    __syncthreads();   // barrier 2
  }

  // ---- epilogue: projection for the final step ----
  if (t < 64) {
    float4 s0 = sh_prod[t], s1 = sh_prod[64 + t], s2 = sh_prod[128 + t], s3 = sh_prod[192 + t];
    float p0 = s0.x + s1.x + s2.x + s3.x;
    float p1 = s0.y + s1.y + s2.y + s3.y;
    float p2 = s0.z + s1.z + s2.z + s3.z;
    float p3 = s0.w + s1.w + s2.w + s3.w;
    #pragma unroll
    for (int off = 32; off; off >>= 1) {
      p0 += __shfl_down(p0, off, 64);
      p1 += __shfl_down(p1, off, 64);
      p2 += __shfl_down(p2, off, 64);
      p3 += __shfl_down(p3, off, 64);
    }
    if (t == 0) {
      p0 += sh_fb[0]; p1 += sh_fb[1]; p2 += sh_fb[2]; p3 += sh_fb[3];
      float nrm = fmaxf(sqrtf(p0 * p0 + p1 * p1 + p2 * p2 + p3 * p3), 1e-12f);
      float inv = 1.f / nrm;
      float4 v = make_float4(p0 * inv, p1 * inv, p2 * inv, p3 * inv);
      if (out_final) *(float4*)(out_final + b * F_) = v;
      else           *(float4*)&g_inter[T_ - 1][b][0] = v;
    }
  }
}

extern "C" void kernel_launch(void* const* d_in, const int* in_sizes, int n_in,
                              void* d_out, int out_size, void* d_ws, size_t ws_size,
                              hipStream_t stream) {
  const float* x   = (const float*)d_in[0];
  const float* wxr = (const float*)d_in[1];
  const float* wxi = (const float*)d_in[2];
  const float* wxj = (const float*)d_in[3];
  const float* wxk = (const float*)d_in[4];
  const float* wxb = (const float*)d_in[5];
  const float* uhr = (const float*)d_in[6];
  const float* uhi = (const float*)d_in[7];
  const float* uhj = (const float*)d_in[8];
  const float* uhk = (const float*)d_in[9];
  const float* fcw = (const float*)d_in[10];
  const float* fcb = (const float*)d_in[11];
  float* out = (float*)d_out;

  (void)hipFuncSetAttribute((const void*)qlstm_layer,
                            hipFuncAttributeMaxDynamicSharedMemorySize, 131072);

  for (int l = 0; l < L_; ++l) {
    qlstm_layer<<<dim3(B_), dim3(256), 131072, stream>>>(
        x, uhr, uhi, uhj, uhk, wxr, wxi, wxj, wxk,
        wxb + l * 4 * H_, fcw + l * H_ * F_, fcb + l * F_, l,
        (l == L_ - 1) ? out : nullptr);
  }
}

// Round 3
// 2460.330 us; speedup vs baseline: 3.3118x; 1.5467x over previous
//
#include <hip/hip_runtime.h>
#include <hip/hip_bf16.h>

#define L_ 2
#define T_ 512
#define B_ 128
#define F_ 4
#define H_ 256

// layer-1 normalized output sequence (fully rewritten every call)
__device__ float g_inter[T_][B_][F_];

// f32 -> bf16 round-to-nearest-even
__device__ __forceinline__ unsigned f2bf(float f) {
  unsigned u = __float_as_uint(f);
  unsigned r = u + 0x7fff + ((u >> 16) & 1);
  return r >> 16;
}
__device__ __forceinline__ float bfl(unsigned v) { return __uint_as_float(v << 16); }
__device__ __forceinline__ float bfh(unsigned v) { return __uint_as_float(v & 0xffff0000u); }
__device__ __forceinline__ float bfs(unsigned short v) { return __uint_as_float(((unsigned)v) << 16); }

__device__ __forceinline__ float fast_sigmoid(float x) { return 1.f / (1.f + __expf(-x)); }
__device__ __forceinline__ float fast_tanh(float x) {
  float a = fabsf(x);
  float e = __expf(2.f * a);
  float r = 1.f - 2.f / (e + 1.f);
  return copysignf(r, x);
}

// W[a*64+p][q*64+u] = sign(a,q) * comp[a^q][p][u]; negative iff bit (a*4+q) of 0x5390
#define QSIGN_MASK 0x5390

// Dynamic LDS layout (bytes)
#define OFF_W    0          // 131072: recurrent weights bf16 [g][d][p8][u][8p x 2B]
#define OFF_PRE  131072     // 16384:  partial pre-acts f32 [g][col(256)][kq(4)]
#define OFF_HB   147456     // 512:    h state bf16 [256]
#define OFF_PROD 147968     // 4096:   projection partials float4 [256]
#define OFF_WXH  152064     // 8192:   expanded Wx bf16 ushort4 [g][col]
#define OFF_X    160256     // 16:     current x (4 f32)
#define OFF_FB   160272     // 16:     fco bias
#define LDS_BYTES 160288

// 1024 threads = 16 waves (4/SIMD). One WG per batch element.
// Phase A: thread (kq=t>>8, gt=(t>>6)&3, u=t&63) computes partial dot over rows
//          p in [kq*16, kq*16+16) for 4 q-columns of gate gt. Wave 4 also reduces
//          the previous step's projection (layer 0 only).
// Phase B: thread t<256 owns hidden index t: sums 4 partials per gate, adds
//          Wx-term + bias, gates, state update, writes h (bf16) and projection products.
__launch_bounds__(1024)
__global__ void qlstm_layer(const float* __restrict__ x_in,
                            const float* __restrict__ uhr, const float* __restrict__ uhi,
                            const float* __restrict__ uhj, const float* __restrict__ uhk,
                            const float* __restrict__ wxr, const float* __restrict__ wxi,
                            const float* __restrict__ wxj, const float* __restrict__ wxk,
                            const float* __restrict__ wb,
                            const float* __restrict__ fw, const float* __restrict__ fb,
                            int layer, float* __restrict__ out_final)
{
  extern __shared__ __align__(16) char lds[];
  float*          pre4 = (float*)(lds + OFF_PRE);
  unsigned short* hbm  = (unsigned short*)(lds + OFF_HB);
  float4*         prod = (float4*)(lds + OFF_PROD);
  ushort4*        wxh  = (ushort4*)(lds + OFF_WXH);
  float*          shx  = (float*)(lds + OFF_X);
  float*          shfb = (float*)(lds + OFF_FB);

  const int t = threadIdx.x;
  const int b = blockIdx.x;

  // ---- stage recurrent weight components into LDS (bf16, p-pairs packed) ----
  {
    const float* C[4] = {uhr, uhi, uhj, uhk};
    for (int pe = t; pe < 32768; pe += 1024) {
      int uu = pe & 63;
      int ph = (pe >> 6) & 31;
      int d  = (pe >> 11) & 3;
      int g  = (pe >> 13) & 3;
      int p0 = ph * 2;
      const float* src = C[d] + ((layer * 4 + g) * 64 + p0) * 64 + uu;
      unsigned lo = f2bf(src[0]);
      unsigned hi = f2bf(src[64]);
      unsigned off = (unsigned)((((g * 4 + d) * 8 + (p0 >> 3)) * 64 + uu) * 16 + (p0 & 7) * 2);
      *(unsigned*)(lds + OFF_W + off) = lo | (hi << 16);
    }
  }
  // ---- stage expanded Wx (one (g,col) per thread) ----
  {
    const float* X[4] = {wxr, wxi, wxj, wxk};
    int g = t >> 8, col = t & 255;
    int q = col >> 6, c = col & 63;
    unsigned short pk[4];
    #pragma unroll
    for (int a = 0; a < 4; ++a) {
      float v = X[a ^ q][(layer * 4 + g) * 64 + c];
      if ((QSIGN_MASK >> (a * 4 + q)) & 1) v = -v;
      pk[a] = (unsigned short)f2bf(v);
    }
    wxh[g * 256 + col] = make_ushort4(pk[0], pk[1], pk[2], pk[3]);
  }
  const int tm = t & 255;
  float wbv[4];
  #pragma unroll
  for (int g = 0; g < 4; ++g) wbv[g] = wb[g * H_ + tm];
  const float4 fw4 = *(const float4*)(fw + tm * 4);
  if (t < 4) shfb[t] = fb[t];
  if (t < H_) hbm[t] = 0;
  float c_state = 0.f;
  __syncthreads();

  const int u    = t & 63;
  const int gt   = (t >> 6) & 3;
  const int kq   = t >> 8;
  const int lane = t & 63;
  const char* wbase = lds + OFF_W + (size_t)((gt * 4) * 8 + kq * 2) * 1024 + u * 16;
  const char* hbase = lds + OFF_HB + kq * 32;

  for (int step = 0; step < T_; ++step) {
    // ---- phase A ----
    if (t == 1023) {
      const float* xp = (layer == 0) ? (x_in + (b * T_ + step) * F_) : &g_inter[step][b][0];
      *(float4*)shx = *(const float4*)xp;
    }
    if (out_final == nullptr && step > 0 && (t >> 6) == 4) {
      // reduce previous step's projection (reads only; writers run after barrier 1)
      float4 s0 = prod[lane], s1 = prod[64 + lane], s2 = prod[128 + lane], s3 = prod[192 + lane];
      float p0 = s0.x + s1.x + s2.x + s3.x;
      float p1 = s0.y + s1.y + s2.y + s3.y;
      float p2 = s0.z + s1.z + s2.z + s3.z;
      float p3 = s0.w + s1.w + s2.w + s3.w;
      #pragma unroll
      for (int off = 32; off; off >>= 1) {
        p0 += __shfl_down(p0, off, 64);
        p1 += __shfl_down(p1, off, 64);
        p2 += __shfl_down(p2, off, 64);
        p3 += __shfl_down(p3, off, 64);
      }
      if (lane == 0) {
        p0 += shfb[0]; p1 += shfb[1]; p2 += shfb[2]; p3 += shfb[3];
        float nrm = fmaxf(sqrtf(p0 * p0 + p1 * p1 + p2 * p2 + p3 * p3), 1e-12f);
        float inv = 1.f / nrm;
        *(float4*)&g_inter[step - 1][b][0] = make_float4(p0 * inv, p1 * inv, p2 * inv, p3 * inv);
      }
    }

    float2 a20 = make_float2(0.f, 0.f), a21 = a20, a22 = a20, a23 = a20;
    #pragma unroll
    for (int hh = 0; hh < 2; ++hh) {
      uint4 hv0 = *(const uint4*)(hbase + 0 * 128 + hh * 16);
      uint4 hv1 = *(const uint4*)(hbase + 1 * 128 + hh * 16);
      uint4 hv2 = *(const uint4*)(hbase + 2 * 128 + hh * 16);
      uint4 hv3 = *(const uint4*)(hbase + 3 * 128 + hh * 16);
      float2 hf[4][4];
      hf[0][0] = make_float2(bfl(hv0.x), bfh(hv0.x));
      hf[0][1] = make_float2(bfl(hv0.y), bfh(hv0.y));
      hf[0][2] = make_float2(bfl(hv0.z), bfh(hv0.z));
      hf[0][3] = make_float2(bfl(hv0.w), bfh(hv0.w));
      hf[1][0] = make_float2(bfl(hv1.x), bfh(hv1.x));
      hf[1][1] = make_float2(bfl(hv1.y), bfh(hv1.y));
      hf[1][2] = make_float2(bfl(hv1.z), bfh(hv1.z));
      hf[1][3] = make_float2(bfl(hv1.w), bfh(hv1.w));
      hf[2][0] = make_float2(bfl(hv2.x), bfh(hv2.x));
      hf[2][1] = make_float2(bfl(hv2.y), bfh(hv2.y));
      hf[2][2] = make_float2(bfl(hv2.z), bfh(hv2.z));
      hf[2][3] = make_float2(bfl(hv2.w), bfh(hv2.w));
      hf[3][0] = make_float2(bfl(hv3.x), bfh(hv3.x));
      hf[3][1] = make_float2(bfl(hv3.y), bfh(hv3.y));
      hf[3][2] = make_float2(bfl(hv3.z), bfh(hv3.z));
      hf[3][3] = make_float2(bfl(hv3.w), bfh(hv3.w));
      #pragma unroll
      for (int d = 0; d < 4; ++d) {
        uint4 wv = *(const uint4*)(wbase + d * 8192 + hh * 1024);
        float2 wf[4];
        wf[0] = make_float2(bfl(wv.x), bfh(wv.x));
        wf[1] = make_float2(bfl(wv.y), bfh(wv.y));
        wf[2] = make_float2(bfl(wv.z), bfh(wv.z));
        wf[3] = make_float2(bfl(wv.w), bfh(wv.w));
        #pragma unroll
        for (int q = 0; q < 4; ++q) {
          const int a = d ^ q;
          const bool neg = (QSIGN_MASK >> (a * 4 + q)) & 1;
          float2* acc = (q == 0) ? &a20 : (q == 1) ? &a21 : (q == 2) ? &a22 : &a23;
          #pragma unroll
          for (int j = 0; j < 4; ++j) {
            if (neg) { acc->x -= wf[j].x * hf[a][j].x; acc->y -= wf[j].y * hf[a][j].y; }
            else     { acc->x += wf[j].x * hf[a][j].x; acc->y += wf[j].y * hf[a][j].y; }
          }
        }
      }
    }
    pre4[((gt * 256 + 0 * 64 + u) << 2) + kq] = a20.x + a20.y;
    pre4[((gt * 256 + 1 * 64 + u) << 2) + kq] = a21.x + a21.y;
    pre4[((gt * 256 + 2 * 64 + u) << 2) + kq] = a22.x + a22.y;
    pre4[((gt * 256 + 3 * 64 + u) << 2) + kq] = a23.x + a23.y;
    __syncthreads();   // barrier 1

    // ---- phase B ----
    if (t < H_) {
      float4 P0 = *(const float4*)(pre4 + ((0 * 256 + t) << 2));
      float4 P1 = *(const float4*)(pre4 + ((1 * 256 + t) << 2));
      float4 P2 = *(const float4*)(pre4 + ((2 * 256 + t) << 2));
      float4 P3 = *(const float4*)(pre4 + ((3 * 256 + t) << 2));
      const float x0 = shx[0], x1 = shx[1], x2 = shx[2], x3 = shx[3];
      ushort4 w0 = wxh[0 * 256 + t], w1 = wxh[1 * 256 + t],
              w2 = wxh[2 * 256 + t], w3 = wxh[3 * 256 + t];
      float pf = P0.x + P0.y + P0.z + P0.w + wbv[0]
               + x0 * bfs(w0.x) + x1 * bfs(w0.y) + x2 * bfs(w0.z) + x3 * bfs(w0.w);
      float pi = P1.x + P1.y + P1.z + P1.w + wbv[1]
               + x0 * bfs(w1.x) + x1 * bfs(w1.y) + x2 * bfs(w1.z) + x3 * bfs(w1.w);
      float po = P2.x + P2.y + P2.z + P2.w + wbv[2]
               + x0 * bfs(w2.x) + x1 * bfs(w2.y) + x2 * bfs(w2.z) + x3 * bfs(w2.w);
      float pc = P3.x + P3.y + P3.z + P3.w + wbv[3]
               + x0 * bfs(w3.x) + x1 * bfs(w3.y) + x2 * bfs(w3.z) + x3 * bfs(w3.w);
      float fg = fast_sigmoid(pf);
      float ig = fast_sigmoid(pi);
      float og = fast_sigmoid(po);
      float cc = fast_tanh(pc);
      c_state = ig * cc + fg * c_state;
      float h = og * fast_tanh(c_state);
      hbm[t] = (unsigned short)f2bf(h);
      if (out_final == nullptr || step == T_ - 1)
        prod[t] = make_float4(h * fw4.x, h * fw4.y, h * fw4.z, h * fw4.w);
    }
    __syncthreads();   // barrier 2
  }

  // ---- epilogue: projection of final step (wave 0) ----
  if (t < 64) {
    float4 s0 = prod[lane], s1 = prod[64 + lane], s2 = prod[128 + lane], s3 = prod[192 + lane];
    float p0 = s0.x + s1.x + s2.x + s3.x;
    float p1 = s0.y + s1.y + s2.y + s3.y;
    float p2 = s0.z + s1.z + s2.z + s3.z;
    float p3 = s0.w + s1.w + s2.w + s3.w;
    #pragma unroll
    for (int off = 32; off; off >>= 1) {
      p0 += __shfl_down(p0, off, 64);
      p1 += __shfl_down(p1, off, 64);
      p2 += __shfl_down(p2, off, 64);
      p3 += __shfl_down(p3, off, 64);
    }
    if (lane == 0) {
      p0 += shfb[0]; p1 += shfb[1]; p2 += shfb[2]; p3 += shfb[3];
      float nrm = fmaxf(sqrtf(p0 * p0 + p1 * p1 + p2 * p2 + p3 * p3), 1e-12f);
      float inv = 1.f / nrm;
      float4 v = make_float4(p0 * inv, p1 * inv, p2 * inv, p3 * inv);
      if (out_final) *(float4*)(out_final + b * F_) = v;
      else           *(float4*)&g_inter[T_ - 1][b][0] = v;
    }
  }
}

extern "C" void kernel_launch(void* const* d_in, const int* in_sizes, int n_in,
                              void* d_out, int out_size, void* d_ws, size_t ws_size,
                              hipStream_t stream) {
  const float* x   = (const float*)d_in[0];
  const float* wxr = (const float*)d_in[1];
  const float* wxi = (const float*)d_in[2];
  const float* wxj = (const float*)d_in[3];
  const float* wxk = (const float*)d_in[4];
  const float* wxb = (const float*)d_in[5];
  const float* uhr = (const float*)d_in[6];
  const float* uhi = (const float*)d_in[7];
  const float* uhj = (const float*)d_in[8];
  const float* uhk = (const float*)d_in[9];
  const float* fcw = (const float*)d_in[10];
  const float* fcb = (const float*)d_in[11];
  float* out = (float*)d_out;

  (void)hipFuncSetAttribute((const void*)qlstm_layer,
                            hipFuncAttributeMaxDynamicSharedMemorySize, LDS_BYTES);

  for (int l = 0; l < L_; ++l) {
    qlstm_layer<<<dim3(B_), dim3(1024), LDS_BYTES, stream>>>(
        x, uhr, uhi, uhj, uhk, wxr, wxi, wxj, wxk,
        wxb + l * 4 * H_, fcw + l * H_ * F_, fcb + l * F_, l,
        (l == L_ - 1) ? out : nullptr);
  }
}